// Round 3
// baseline (287.408 us; speedup 1.0000x reference)
//
#include <hip/hip_runtime.h>

#define FDIM   128
#define HEADS  4
#define ALPHA  0.2f
#define DMASK  0x03FFFFFF     // low 26 bits = dst
#define PT     4096           // partition tile (edges per block)
#define NBMAX  1568           // max fine buckets supported by static LDS

typedef float v2f __attribute__((ext_vector_type(2)));
typedef __attribute__((ext_vector_type(8))) short bf16x8;
typedef __attribute__((ext_vector_type(4))) float f32x4;
typedef __attribute__((ext_vector_type(4))) unsigned u32x4;

// ------- per-node scores + bf16-pack of x (+ fine-bucket histogram slice) ----
// Multi-value butterfly reduction: 10 shuffles/wave instead of 48.
__global__ __launch_bounds__(256) void score_kernel(
    const float* __restrict__ x, const float* __restrict__ W,
    const float* __restrict__ a, float* __restrict__ s_src,
    float* __restrict__ s_dst, unsigned int* __restrict__ xb,
    const int* __restrict__ src, int* __restrict__ hist,
    int E, int HB, int n) {
  __shared__ int h[NBMAX];
  int lane = threadIdx.x & 63;
  int node = (blockIdx.x << 2) + (threadIdx.x >> 6);
  if (node < n) {
    const float2* x2 = (const float2*)x;
    const float2* W2 = (const float2*)W;
    const float2* a2 = (const float2*)a;
    float2 xv = x2[(size_t)node * 64 + lane];

    // bf16 pack (round-to-nearest-even)
    unsigned int u0 = __float_as_uint(xv.x);
    unsigned int u1 = __float_as_uint(xv.y);
    u0 += 0x7fffu + ((u0 >> 16) & 1u);
    u1 += 0x7fffu + ((u1 >> 16) & 1u);
    xb[(size_t)node * 64 + lane] = (u0 >> 16) | (u1 & 0xffff0000u);

    float p[8];   // p[0..3] = rs per head, p[4..7] = rd per head
#pragma unroll
    for (int k = 0; k < HEADS; k++) {
      float2 wv = W2[k * 64 + lane];
      float hx = xv.x * wv.x, hy = xv.y * wv.y;
      float2 as_ = a2[k * 128 + lane];        // a[k, 0:F]
      float2 ad_ = a2[k * 128 + 64 + lane];   // a[k, F:2F]
      p[k]     = hx * as_.x + hy * as_.y;
      p[4 + k] = hx * ad_.x + hy * ad_.y;
    }

    bool h5 = (lane & 32) != 0;
    float q[4];
#pragma unroll
    for (int k = 0; k < 4; k++) {
      float send = h5 ? p[k] : p[4 + k];
      float got = __shfl_xor(send, 32);
      q[k] = (h5 ? p[4 + k] : p[k]) + got;
    }
    bool h4 = (lane & 16) != 0;
    float r[2];
#pragma unroll
    for (int j = 0; j < 2; j++) {
      float send = h4 ? q[j] : q[2 + j];
      float got = __shfl_xor(send, 16);
      r[j] = (h4 ? q[2 + j] : q[j]) + got;
    }
    bool h3 = (lane & 8) != 0;
    float send = h3 ? r[0] : r[1];
    float got = __shfl_xor(send, 8);
    float v = (h3 ? r[1] : r[0]) + got;
    v += __shfl_xor(v, 1);
    v += __shfl_xor(v, 2);
    v += __shfl_xor(v, 4);
    if ((lane & 7) == 0) {
      int s = lane >> 3;
      if (s < 4) s_src[node * HEADS + s] = v;
      else       s_dst[node * HEADS + (s - 4)] = v;
    }
  }

  // histogram slice: blocks [0, HB) each cover 8192 edges with LDS pre-agg
  int b = blockIdx.x;
  if (b < HB) {
    int t = threadIdx.x;
    int NB = (n + 63) >> 6;
    for (int i = t; i < NB; i += 256) h[i] = 0;
    __syncthreads();
    int base = b * 8192;
#pragma unroll 4
    for (int j = 0; j < 32; j++) {
      int i = base + j * 256 + t;
      if (i < E) atomicAdd(&h[src[i] >> 6], 1);
    }
    __syncthreads();
    for (int i = t; i < NB; i += 256)
      if (h[i]) atomicAdd(&hist[i], h[i]);
  }
}

// ---------------- exclusive scan of NB (<=2048) bucket counts: 1 block -------
__global__ __launch_bounds__(256) void scan_kernel(const int* __restrict__ hist,
                                                   int* __restrict__ fine_ptr,
                                                   int* __restrict__ cursor,
                                                   int NB, int E) {
  __shared__ int lds[256];
  int t = threadIdx.x;
  int loc[8];
  int s = 0;
#pragma unroll
  for (int j = 0; j < 8; j++) {
    int idx = t * 8 + j;
    loc[j] = (idx < NB) ? hist[idx] : 0;
    s += loc[j];
  }
  lds[t] = s;
  __syncthreads();
  for (int off = 1; off < 256; off <<= 1) {
    int xv = (t >= off) ? lds[t - off] : 0;
    __syncthreads();
    lds[t] += xv;
    __syncthreads();
  }
  int run = lds[t] - s;
#pragma unroll
  for (int j = 0; j < 8; j++) {
    int idx = t * 8 + j;
    if (idx < NB) {
      fine_ptr[idx] = run;
      cursor[idx]   = run;
    }
    run += loc[j];
  }
  if (t == 0) fine_ptr[NB] = E;
}

// ---------------- partition: tile-sort 4096 edges by fine bucket in LDS ------
__global__ __launch_bounds__(256) void partition_kernel(
    const int* __restrict__ src, const int* __restrict__ dst,
    const float* __restrict__ adj, int* __restrict__ cursor,
    int2* __restrict__ ebuf, int E, int NB) {
  __shared__ int h[NBMAX];
  __shared__ int sc[NBMAX];
  __shared__ int bg[NBMAX];
  __shared__ unsigned short keyarr[PT];
  __shared__ int2 es[PT];
  __shared__ int lds[256];

  int t = threadIdx.x;
  int base = blockIdx.x * PT;
  for (int i = t; i < NB; i += 256) h[i] = 0;
  __syncthreads();

  int ssrc[16];
#pragma unroll
  for (int j = 0; j < 16; j++) {
    int i = base + j * 256 + t;
    ssrc[j] = (i < E) ? src[i] : -1;
    if (ssrc[j] >= 0) atomicAdd(&h[ssrc[j] >> 6], 1);
  }
  __syncthreads();

  int loc[8];
  int s = 0;
#pragma unroll
  for (int j = 0; j < 8; j++) {
    int idx = t * 8 + j;
    loc[j] = (idx < NB) ? h[idx] : 0;
    s += loc[j];
  }
  lds[t] = s;
  __syncthreads();
  for (int off = 1; off < 256; off <<= 1) {
    int xv = (t >= off) ? lds[t - off] : 0;
    __syncthreads();
    lds[t] += xv;
    __syncthreads();
  }
  int run = lds[t] - s;
#pragma unroll
  for (int j = 0; j < 8; j++) {
    int idx = t * 8 + j;
    if (idx < NB) sc[idx] = run;
    run += loc[j];
  }
  __syncthreads();

  for (int i = t; i < NB; i += 256)
    if (h[i]) bg[i] = atomicAdd(&cursor[i], h[i]);
  __syncthreads();

#pragma unroll
  for (int j = 0; j < 16; j++) {
    if (ssrc[j] >= 0) {
      int i = base + j * 256 + t;
      int k = ssrc[j] >> 6;
      int slot = atomicAdd(&sc[k], 1);
      int2 pk;
      pk.x = (int)(((unsigned)(ssrc[j] & 63) << 26) | (unsigned)dst[i]);
      pk.y = __float_as_int(adj[i]);
      es[slot] = pk;
      keyarr[slot] = (unsigned short)k;
    }
  }
  __syncthreads();

  int tc = E - base; if (tc > PT) tc = PT;
  for (int s2 = t; s2 < tc; s2 += 256) {
    int k = keyarr[s2];
    int rank = s2 - (sc[k] - h[k]);
    ebuf[bg[k] + rank] = es[s2];
  }
}

// ---------------- aggregate: MFMA edition ------------------------------------
// One block per 16-node quarter-bucket; each of 4 waves owns a 4-node group.
// Per 32-edge window:
//   A (16x32 bf16, hi+lo split) rows = node_in_group*4+head, owner-masked ev.
//   B (32x16 bf16) = gathered x rows, staged to wave-private LDS via
//     global_load_lds (linear dest), read back transposed with dword reads +
//     v_perm packs.  8 n-chunks cover F=128.  +1 ones-B MFMA pair = rowsums.
// D rows land as (lane>>4)=node, reg=head, col=feature (m89-verified layout),
// so the epilogue is pure per-lane math -- no shuffles at all.
// Main loop is barrier-free (all LDS traffic wave-private; es is read-only
// after the preamble).
__global__ __launch_bounds__(256, 4) void aggregate_kernel(
    const unsigned int* __restrict__ xb, const float* __restrict__ W,
    const float* __restrict__ s_src, const float* __restrict__ s_dst,
    const int* __restrict__ fine_ptr, const int2* __restrict__ ebuf,
    float* __restrict__ out, int n) {
  __shared__ int2  es[512];
  __shared__ unsigned short xrow[4][32][128];  // [wave][edge][feature] bf16
  __shared__ float evls[4][192];               // [wave][edge*6 + head] (pad 6)
  __shared__ int   own_w[4][32];               // [wave][edge] owner in group
  __shared__ int   nbeg[17];
  __shared__ int   nrun[16];
  __shared__ int   h[16];

  int t = threadIdx.x, bb = blockIdx.x;
  int b0 = bb >> 2, qtr = bb & 3;      // parent 64-bucket, which quarter
  int lane = t & 63, wid = t >> 6;
  int beg = fine_ptr[b0];
  int L   = fine_ptr[b0 + 1] - beg;

  // ---- preamble: filter quarter, count per node, scatter into es ----
  if (t < 16) h[t] = 0;
  __syncthreads();
  for (int i = t; i < L; i += 256) {
    int kk = (unsigned)ebuf[beg + i].x >> 26;
    if ((kk >> 4) == qtr) atomicAdd(&h[kk & 15], 1);
  }
  __syncthreads();
  if (t < 16) {
    int v = h[t];
#pragma unroll
    for (int off = 1; off < 16; off <<= 1) {
      int u = __shfl_up(v, off);
      if (lane >= off) v += u;
    }
    nbeg[t + 1] = v;
    nrun[t] = v - h[t];
    if (t == 0) nbeg[0] = 0;
  }
  __syncthreads();
  for (int i = t; i < L; i += 256) {
    int2 pk = ebuf[beg + i];
    int kk = (unsigned)pk.x >> 26;
    if ((kk >> 4) == qtr) {
      int slot = atomicAdd(&nrun[kk & 15], 1);
      es[slot] = pk;
    }
  }
  __syncthreads();

  int el = lane & 31;                  // edge slot in window
  int hp = lane >> 5;                  // head pair for ev compute
  int kb = (lane >> 4) << 3;           // k-base for A/B fragments
  int ha = lane & 3;                   // A-row head
  int na = (lane & 15) >> 2;           // A-row node-in-group
  unsigned dsel = (lane & 1) ? 0x07060302u : 0x05040100u;

  bf16x8 bones;
#pragma unroll
  for (int j = 0; j < 8; j++) bones[j] = (short)0x3F80;  // bf16 1.0

  f32x4 acc[8];
#pragma unroll
  for (int c = 0; c < 8; c++) acc[c] = (f32x4){0.f, 0.f, 0.f, 0.f};
  f32x4 accR = (f32x4){0.f, 0.f, 0.f, 0.f};

  int wbase = nbeg[wid * 4];
  int wend  = nbeg[wid * 4 + 4];
  int gb = (b0 << 6) + (qtr << 4) + wid * 4;   // first global node of group

  for (int cb = wbase; cb < wend; cb += 32) {
    int rem = wend - cb;
    int2 pk{0, 0};
    if (el < rem) pk = es[cb + el];

    // ---- issue 32 row loads direct-to-LDS (wave-private region) ----
    asm volatile("s_waitcnt lgkmcnt(0)" ::: "memory");
#pragma unroll
    for (int j = 0; j < 32; j++) {
      int dd = __builtin_amdgcn_readlane(pk.x, j) & DMASK;
      __builtin_amdgcn_global_load_lds(
          (const __attribute__((address_space(1))) unsigned int*)
              (xb + (((size_t)(unsigned)dd) << 6) + lane),
          (__attribute__((address_space(3))) unsigned int*)(&xrow[wid][j][0]),
          4, 0, 0);
    }

    // ---- ev phase (covers load latency) ----
    unsigned kk = (unsigned)pk.x >> 26;
    int own_e = (int)(kk & 3);
    int dv = pk.x & DMASK;
    int ng = (b0 << 6) + (qtr << 4) + (int)(kk & 15);
    float2 sv  = *(const float2*)&s_src[ng * 4 + 2 * hp];
    float2 dvv = *(const float2*)&s_dst[dv * 4 + 2 * hp];
    float adjv = __int_as_float(pk.y);
    float s0 = sv.x + dvv.x; s0 = (s0 >= 0.f) ? s0 : ALPHA * s0;
    float s1 = sv.y + dvv.y; s1 = (s1 >= 0.f) ? s1 : ALPHA * s1;
    float e0 = __expf(s0) * adjv;
    float e1 = __expf(s1) * adjv;
    if (el >= rem) { e0 = 0.f; e1 = 0.f; }   // padded: force exact 0 (no NaN)
    *(float2*)&evls[wid][el * 6 + 2 * hp] = float2{e0, e1};
    own_w[wid][el] = own_e;

    // ---- A fragments: owner-masked ev, bf16 hi + residual lo ----
    unsigned hw0, hw1, hw2, hw3, lw0, lw1, lw2, lw3;
#define ABUILD(JP, HW, LW) {                                          \
      int k0 = kb + 2 * (JP), k1 = k0 + 1;                            \
      float m0 = evls[wid][k0 * 6 + ha];                              \
      float m1 = evls[wid][k1 * 6 + ha];                              \
      m0 = (own_w[wid][k0] == na) ? m0 : 0.f;                         \
      m1 = (own_w[wid][k1] == na) ? m1 : 0.f;                         \
      unsigned u0 = __float_as_uint(m0), u1 = __float_as_uint(m1);    \
      unsigned r0 = u0 + 0x7fffu + ((u0 >> 16) & 1u);                 \
      unsigned r1 = u1 + 0x7fffu + ((u1 >> 16) & 1u);                 \
      HW = __builtin_amdgcn_perm(r1, r0, 0x07060302u);                \
      float l0 = m0 - __uint_as_float(r0 & 0xffff0000u);              \
      float l1 = m1 - __uint_as_float(r1 & 0xffff0000u);              \
      LW = __builtin_amdgcn_perm(__float_as_uint(l1),                 \
                                 __float_as_uint(l0), 0x07060302u); }
    ABUILD(0, hw0, lw0)
    ABUILD(1, hw1, lw1)
    ABUILD(2, hw2, lw2)
    ABUILD(3, hw3, lw3)
#undef ABUILD
    bf16x8 ahi = __builtin_bit_cast(bf16x8, (u32x4){hw0, hw1, hw2, hw3});
    bf16x8 alo = __builtin_bit_cast(bf16x8, (u32x4){lw0, lw1, lw2, lw3});

    // ---- B fragments + MFMAs ----
    asm volatile("s_waitcnt vmcnt(0)" ::: "memory");  // xrow landed
    int fb = lane & 14;   // ((lane&15) & ~1) -> even feature within chunk
#pragma unroll
    for (int cc = 0; cc < 8; cc++) {
      unsigned dw[8];
#pragma unroll
      for (int j = 0; j < 8; j++)
        dw[j] = *(const unsigned*)&xrow[wid][kb + j][cc * 16 + fb];
      u32x4 bw = { __builtin_amdgcn_perm(dw[1], dw[0], dsel),
                   __builtin_amdgcn_perm(dw[3], dw[2], dsel),
                   __builtin_amdgcn_perm(dw[5], dw[4], dsel),
                   __builtin_amdgcn_perm(dw[7], dw[6], dsel) };
      bf16x8 bfrag = __builtin_bit_cast(bf16x8, bw);
      acc[cc] = __builtin_amdgcn_mfma_f32_16x16x32_bf16(ahi, bfrag, acc[cc], 0, 0, 0);
      acc[cc] = __builtin_amdgcn_mfma_f32_16x16x32_bf16(alo, bfrag, acc[cc], 0, 0, 0);
    }
    accR = __builtin_amdgcn_mfma_f32_16x16x32_bf16(ahi, bones, accR, 0, 0, 0);
    accR = __builtin_amdgcn_mfma_f32_16x16x32_bf16(alo, bones, accR, 0, 0, 0);
  }

  // ---- epilogue: pure per-lane; node = lane>>4, head = acc reg ----
  float rinv0 = __builtin_amdgcn_rcpf(accR[0]);
  float rinv1 = __builtin_amdgcn_rcpf(accR[1]);
  float rinv2 = __builtin_amdgcn_rcpf(accR[2]);
  float rinv3 = __builtin_amdgcn_rcpf(accR[3]);
  int ng4 = gb + (lane >> 4);
  bool valid = ng4 < n;
  int fl = lane & 15;
#pragma unroll
  for (int cc = 0; cc < 8; cc++) {
    int f = cc * 16 + fl;
    float o = 0.f;
    float v0 = acc[cc][0] * W[0 * 128 + f] * rinv0;
    o += (v0 > 0.f) ? v0 : (__expf(v0) - 1.f);
    float v1 = acc[cc][1] * W[1 * 128 + f] * rinv1;
    o += (v1 > 0.f) ? v1 : (__expf(v1) - 1.f);
    float v2 = acc[cc][2] * W[2 * 128 + f] * rinv2;
    o += (v2 > 0.f) ? v2 : (__expf(v2) - 1.f);
    float v3 = acc[cc][3] * W[3 * 128 + f] * rinv3;
    o += (v3 > 0.f) ? v3 : (__expf(v3) - 1.f);
    if (valid) out[(size_t)ng4 * 128 + f] = o * 0.25f;
  }
}

extern "C" void kernel_launch(void* const* d_in, const int* in_sizes, int n_in,
                              void* d_out, int out_size, void* d_ws, size_t ws_size,
                              hipStream_t stream) {
  const float* x   = (const float*)d_in[0];
  const int*   edg = (const int*)d_in[1];
  const float* adj = (const float*)d_in[2];
  const float* W   = (const float*)d_in[3];
  const float* a   = (const float*)d_in[4];
  float* out = (float*)d_out;

  int E = in_sizes[2];
  int n = in_sizes[0] / FDIM;
  const int* src = edg;
  const int* dst = edg + E;
  int NB = (n + 63) >> 6;              // fine buckets of 64 nodes (<= NBMAX)
  int HB = (E + 8191) / 8192;          // histogram tiles

  auto align = [](size_t v) { return (v + 255) & ~(size_t)255; };
  char* ws = (char*)d_ws;
  int*   fine_ptr = (int*)ws;          ws += align((size_t)(NB + 1) * 4);
  int*   cursor   = (int*)ws;          ws += align((size_t)NB * 4);
  int*   hist     = (int*)ws;          ws += align((size_t)NB * 4);
  int2*  ebuf     = (int2*)ws;         ws += align((size_t)E * 8);
  float* s_src    = (float*)ws;        ws += align((size_t)n * HEADS * 4);
  float* s_dst    = (float*)ws;        ws += align((size_t)n * HEADS * 4);
  unsigned int* xb = (unsigned int*)ws; ws += align((size_t)n * 64 * 4);

  hipMemsetAsync(hist, 0, (size_t)NB * 4, stream);

  score_kernel<<<(n + 3) / 4, 256, 0, stream>>>(x, W, a, s_src, s_dst, xb,
                                                src, hist, E, HB, n);
  scan_kernel<<<1, 256, 0, stream>>>(hist, fine_ptr, cursor, NB, E);
  partition_kernel<<<(E + PT - 1) / PT, 256, 0, stream>>>(src, dst, adj, cursor,
                                                          ebuf, E, NB);
  aggregate_kernel<<<NB * 4, 256, 0, stream>>>(xb, W, s_src, s_dst, fine_ptr,
                                               ebuf, out, n);
}